// Round 14
// baseline (80.710 us; speedup 1.0000x reference)
//
#include <hip/hip_runtime.h>

#define GRID_N 16384
#define NLAYERS 8
#define NPOS 32
#define BATCH 32
#define MW 4096          // output width
#define TILE 32
#define HALO 16          // 2 * NLAYERS
#define WBUF 64          // TILE + 2*HALO = one wave of column slots
#define ROWP 36          // gate row stride: 144B; b128 is 16-lane-phased -> 2-way max = free

typedef float f2 __attribute__((ext_vector_type(2)));

// DPP wave shifts: data from lane n-1 / n+1 (boundary lanes read 0; halo absorbs).
__device__ __forceinline__ float dpp_shr1(float v) {   // lane n <- lane n-1
    return __builtin_bit_cast(float, __builtin_amdgcn_update_dpp(
        0, __builtin_bit_cast(int, v), 0x138, 0xF, 0xF, true));
}
__device__ __forceinline__ float dpp_shl1(float v) {   // lane n <- lane n+1
    return __builtin_bit_cast(float, __builtin_amdgcn_update_dpp(
        0, __builtin_bit_cast(int, v), 0x130, 0xF, 0xF, true));
}
__device__ __forceinline__ f2 shr1(f2 v) { f2 r; r.x = dpp_shr1(v.x); r.y = dpp_shr1(v.y); return r; }
__device__ __forceinline__ f2 shl1(f2 v) { f2 r; r.x = dpp_shl1(v.x); r.y = dpp_shl1(v.y); return r; }

__device__ __forceinline__ float sigm(float v) {
    return __builtin_amdgcn_rcpf(1.0f + __expf(-v));
}

// LDS-only barrier (no vmcnt drain): barriers here guard only LDS gate
// staging; in-flight global loads are consumed by their issuing wave.
__device__ __forceinline__ void barrier_lds_only() {
    asm volatile("s_waitcnt lgkmcnt(0)\n\ts_barrier" ::: "memory");
}

// v14 = v13 pipeline on 8-BATCH waves: DS was the binding warm term
// (per CU-layer: 16 waves x 8 ds_read_b128 x 12cyc = 5.1us > VALU 3us).
// Wave = 8 batches x 64 col-slots -> same 8 gate reads serve 2x the cells:
// DS instr/CU halves. 512 blocks x 256 threads (4 waves), 2 blocks/CU,
// 2 waves/SIMD (occupancy traded for DS issue). Level-0 of the s4-first
// tree computed for all 4 batch-pairs from each b128 chunk (read LDS once);
// pairs then contracted sequentially. State in VGPRs via DPP; twl[2]
// rolling prefetch with pfA/pfB reg double-buffer; lgkm-only barriers.
__global__ __launch_bounds__(256, 2) void ASIC_44186623541335_kernel(
    const float* __restrict__ x,    // (32, 4096)
    const float* __restrict__ tg,   // (8, 32, 16384) raw logits
    float* __restrict__ out)        // (32, 4096)
{
    __shared__ __align__(16) float twl[2][WBUF][ROWP];   // 18.4 KB, gates only

    const int tid = threadIdx.x;
    const int tx  = tid & 63;        // column slot (lane)
    const int w   = tid >> 6;        // wave 0..3 -> batches 8w..8w+7, gate cols 8w..8w+7
    const int c0  = 8 * w;
    const int start = blockIdx.x * TILE;
    const int gcol  = (start - HALO + tx) & (GRID_N - 1);

    // ---- x loads first (oldest) ----
    const bool on = (gcol & 3) == 0;
    const int  m  = gcol >> 2;
    float xv[8];
    #pragma unroll
    for (int k = 0; k < 8; ++k)
        xv[k] = on ? x[(c0 + k) * MW + m] : 0.0f;

    // ---- gate prefetch, double-buffered: group = 2 layers x 8 gate-cols ----
    float pfA[16], pfB[16];
    #pragma unroll
    for (int ll = 0; ll < 2; ++ll)
        #pragma unroll
        for (int k = 0; k < 8; ++k)
            pfA[ll * 8 + k] = tg[((size_t)ll * NPOS + c0 + k) * GRID_N + gcol];
    #pragma unroll
    for (int ll = 0; ll < 2; ++ll)
        #pragma unroll
        for (int k = 0; k < 8; ++k)
            pfB[ll * 8 + k] = tg[((size_t)(2 + ll) * NPOS + c0 + k) * GRID_N + gcol];

    // ---- init state IN REGISTERS: 8 batches = 4 f2 pairs ----
    f2 S[4];
    #pragma unroll
    for (int q = 0; q < 4; ++q) { S[q].x = xv[2 * q]; S[q].y = xv[2 * q + 1]; }

    // ---- stage group 0 (waits only on pfA); issue group-2 into free pfA ----
    #pragma unroll
    for (int ll = 0; ll < 2; ++ll)
        #pragma unroll
        for (int h4 = 0; h4 < 2; ++h4) {
            float4 sg;
            sg.x = sigm(pfA[ll * 8 + 4 * h4 + 0]);
            sg.y = sigm(pfA[ll * 8 + 4 * h4 + 1]);
            sg.z = sigm(pfA[ll * 8 + 4 * h4 + 2]);
            sg.w = sigm(pfA[ll * 8 + 4 * h4 + 3]);
            *(float4*)&twl[ll][tx][c0 + 4 * h4] = sg;
        }
    #pragma unroll
    for (int ll = 0; ll < 2; ++ll)
        #pragma unroll
        for (int k = 0; k < 8; ++k)
            pfA[ll * 8 + k] = tg[((size_t)(4 + ll) * NPOS + c0 + k) * GRID_N + gcol];
    barrier_lds_only();   // group-0 gates visible; later bursts stay in flight

    #pragma unroll
    for (int g = 0; g < 4; ++g) {          // 4 groups of 2 layers
        #pragma unroll
        for (int ll = 0; ll < 2; ++ll) {
            // neighbor states via DPP wave shifts (VALU, independent of LDS)
            f2 s0v[4], s1v[4], s3v[4], s4v[4];
            #pragma unroll
            for (int q = 0; q < 4; ++q) {
                s1v[q] = shr1(S[q]);      // column n-1
                s0v[q] = shr1(s1v[q]);    // column n-2
                s3v[q] = shl1(S[q]);      // column n+1
                s4v[q] = shl1(s3v[q]);    // column n+2
            }

            // level 0 (contract s4): each b128 chunk read ONCE, feeds all
            // 4 batch-pairs immediately (fine-grained lgkmcnt interleave).
            f2 u[4][16];
            #pragma unroll
            for (int k = 0; k < 8; ++k) {
                const float4 t4 = *(const float4*)&twl[ll][tx][4 * k];
                const float dA = t4.y - t4.x;    // d[2k]   (batch-invariant)
                const float dB = t4.w - t4.z;    // d[2k+1]
                #pragma unroll
                for (int q = 0; q < 4; ++q) {
                    u[q][2 * k]     = __builtin_elementwise_fma(s4v[q], (f2)dA, (f2)t4.x);
                    u[q][2 * k + 1] = __builtin_elementwise_fma(s4v[q], (f2)dB, (f2)t4.z);
                }
            }

            // levels 1..4: contract s3, s2(center), s1, s0 — adjacent pairs
            #pragma unroll
            for (int q = 0; q < 4; ++q) {
                f2* uq = u[q];
                #pragma unroll
                for (int r = 0; r < 8; ++r)
                    uq[r] = __builtin_elementwise_fma(s3v[q], uq[2 * r + 1] - uq[2 * r], uq[2 * r]);
                #pragma unroll
                for (int r = 0; r < 4; ++r)
                    uq[r] = __builtin_elementwise_fma(S[q],   uq[2 * r + 1] - uq[2 * r], uq[2 * r]);
                #pragma unroll
                for (int r = 0; r < 2; ++r)
                    uq[r] = __builtin_elementwise_fma(s1v[q], uq[2 * r + 1] - uq[2 * r], uq[2 * r]);
                f2 rv = __builtin_elementwise_fma(s0v[q], uq[1] - uq[0], uq[0]);
                rv = __builtin_elementwise_min(__builtin_elementwise_max(rv, (f2)0.0f), (f2)1.0f);
                S[q] = rv;
            }
        }

        if (g < 3) {
            barrier_lds_only();   // all waves done reading this group's gates
            // stage next group from the bank loaded ~2 groups ago
            float* pfs = (g & 1) ? pfA : pfB;
            #pragma unroll
            for (int ll = 0; ll < 2; ++ll)
                #pragma unroll
                for (int h4 = 0; h4 < 2; ++h4) {
                    float4 sg;
                    sg.x = sigm(pfs[ll * 8 + 4 * h4 + 0]);
                    sg.y = sigm(pfs[ll * 8 + 4 * h4 + 1]);
                    sg.z = sigm(pfs[ll * 8 + 4 * h4 + 2]);
                    sg.w = sigm(pfs[ll * 8 + 4 * h4 + 3]);
                    *(float4*)&twl[ll][tx][c0 + 4 * h4] = sg;
                }
            if (g < 1) {          // issue group-3 loads into the free bank
                #pragma unroll
                for (int ll = 0; ll < 2; ++ll)
                    #pragma unroll
                    for (int k = 0; k < 8; ++k)
                        pfB[ll * 8 + k] = tg[((size_t)(6 + ll) * NPOS + c0 + k) * GRID_N + gcol];
            }
            barrier_lds_only();   // next group's gates visible
        }
    }

    // ---- output straight from registers: state[:, ::4] for owned columns ----
    const int rel = tx - HALO;
    if (rel >= 0 && rel < TILE && (rel & 3) == 0) {
        const int mo = (start >> 2) + (rel >> 2);
        #pragma unroll
        for (int q = 0; q < 4; ++q) {
            out[(c0 + 2 * q)     * MW + mo] = S[q].x;
            out[(c0 + 2 * q + 1) * MW + mo] = S[q].y;
        }
    }
}

extern "C" void kernel_launch(void* const* d_in, const int* in_sizes, int n_in,
                              void* d_out, int out_size, void* d_ws, size_t ws_size,
                              hipStream_t stream) {
    const float* x  = (const float*)d_in[0];   // (32, 4096)
    const float* tg = (const float*)d_in[1];   // (8, 32, 16384)
    float* out = (float*)d_out;                // (32, 4096)
    ASIC_44186623541335_kernel<<<GRID_N / TILE, 256, 0, stream>>>(x, tg, out);
}

// Round 15
// 80.384 us; speedup vs baseline: 1.0041x; 1.0041x over previous
//
#include <hip/hip_runtime.h>

#define GRID_N 16384
#define NLAYERS 8
#define NPOS 32
#define BATCH 32
#define MW 4096          // output width
#define TILE 32
#define HALO 16          // 2 * NLAYERS
#define WBUF 64          // TILE + 2*HALO = one wave of column slots
#define ROWP 36          // gate row stride: 144B; b128 is 16-lane-phased -> 2-way max = free

typedef float f2 __attribute__((ext_vector_type(2)));

// DPP wave shifts: data from lane n-1 / n+1 (boundary lanes read 0; halo absorbs).
__device__ __forceinline__ float dpp_shr1(float v) {   // lane n <- lane n-1
    return __builtin_bit_cast(float, __builtin_amdgcn_update_dpp(
        0, __builtin_bit_cast(int, v), 0x138, 0xF, 0xF, true));
}
__device__ __forceinline__ float dpp_shl1(float v) {   // lane n <- lane n+1
    return __builtin_bit_cast(float, __builtin_amdgcn_update_dpp(
        0, __builtin_bit_cast(int, v), 0x130, 0xF, 0xF, true));
}
__device__ __forceinline__ f2 shr1(f2 v) { f2 r; r.x = dpp_shr1(v.x); r.y = dpp_shr1(v.y); return r; }
__device__ __forceinline__ f2 shl1(f2 v) { f2 r; r.x = dpp_shl1(v.x); r.y = dpp_shl1(v.y); return r; }

__device__ __forceinline__ float sigm(float v) {
    return __builtin_amdgcn_rcpf(1.0f + __expf(-v));
}

// Gate for layer l is consumed (its output feeds the final valid cone
// lanes 16..47) only for lanes tx in [2+2l, 62-2l). Loads outside are
// exec-masked off -> ~28% of gate HBM traffic never issued. Masked lanes
// keep pf=0 -> sigm(0)=0.5 lands in twl halo that no surviving value reads.
__device__ __forceinline__ bool gate_needed(int tx, int l) {
    return (tx >= 2 + 2 * l) && (tx < 62 - 2 * l);
}

// v15 = v10 (best: rolling 2-layer gate cadence, s4-first chunked tree,
// 512x512, state in VGPRs via DPP) + two HBM-traffic cuts:
//  (a) per-layer exec-masked gate loads (28% of gate fetch was for halo
//      col-layers whose output never reaches the valid cone);
//  (b) XCD-contiguous tile swizzle: dispatch is round-robin over 8 XCDs,
//      so tile = (bid%8)*64 + bid/8 gives each XCD 64 ADJACENT tiles ->
//      halo gate segments shared between neighbor tiles hit the same L2.
__global__ __launch_bounds__(512, 4) void ASIC_44186623541335_kernel(
    const float* __restrict__ x,    // (32, 4096)
    const float* __restrict__ tg,   // (8, 32, 16384) raw logits
    float* __restrict__ out)        // (32, 4096)
{
    __shared__ __align__(16) float twl[2][WBUF][ROWP];   // 18.4 KB, gates only

    const int tid = threadIdx.x;
    const int tx  = tid & 63;        // column slot (lane)
    const int w   = tid >> 6;        // wave 0..7 -> batches 4w..4w+3, gate cols 4w..4w+3
    const int c0  = 4 * w;
    const int bid  = blockIdx.x;
    const int tile = (bid & 7) * 64 + (bid >> 3);   // XCD-contiguous swizzle
    const int start = tile * TILE;
    const int gcol  = (start - HALO + tx) & (GRID_N - 1);

    // ---- x loads first (oldest; exec-masked to embedded columns) ----
    const bool on = (gcol & 3) == 0;
    const int  m  = gcol >> 2;
    float xv[4];
    #pragma unroll
    for (int k = 0; k < 4; ++k)
        xv[k] = on ? x[(c0 + k) * MW + m] : 0.0f;

    // ---- load gate logits for group 0 (layers 0,1), masked per layer ----
    float pf[8];
    #pragma unroll
    for (int ll = 0; ll < 2; ++ll) {
        const bool need = gate_needed(tx, ll);
        #pragma unroll
        for (int k = 0; k < 4; ++k)
            pf[ll * 4 + k] = need ? tg[((size_t)ll * NPOS + c0 + k) * GRID_N + gcol] : 0.0f;
    }

    // ---- init state IN REGISTERS ----
    f2 S[2];
    S[0].x = xv[0]; S[0].y = xv[1];
    S[1].x = xv[2]; S[1].y = xv[3];

    // ---- stage group 0 (sigmoid once); prefetch group 1 (layers 2,3) ----
    #pragma unroll
    for (int ll = 0; ll < 2; ++ll) {
        float4 sg;
        sg.x = sigm(pf[ll * 4 + 0]);
        sg.y = sigm(pf[ll * 4 + 1]);
        sg.z = sigm(pf[ll * 4 + 2]);
        sg.w = sigm(pf[ll * 4 + 3]);
        *(float4*)&twl[ll][tx][c0] = sg;
    }
    #pragma unroll
    for (int ll = 0; ll < 2; ++ll) {
        const bool need = gate_needed(tx, 2 + ll);
        #pragma unroll
        for (int k = 0; k < 4; ++k)
            pf[ll * 4 + k] = need ? tg[((size_t)(2 + ll) * NPOS + c0 + k) * GRID_N + gcol] : 0.0f;
    }
    __syncthreads();   // group-0 gates visible

    #pragma unroll
    for (int g = 0; g < 4; ++g) {          // 4 groups of 2 layers
        #pragma unroll
        for (int ll = 0; ll < 2; ++ll) {
            // neighbor states via DPP wave shifts (VALU, independent of LDS)
            f2 s0v[2], s1v[2], s3v[2], s4v[2];
            #pragma unroll
            for (int q = 0; q < 2; ++q) {
                s1v[q] = shr1(S[q]);      // column n-1
                s0v[q] = shr1(s1v[q]);    // column n-2
                s3v[q] = shl1(S[q]);      // column n+1
                s4v[q] = shl1(s3v[q]);    // column n+2
            }

            // level 0 (contract s4): chunk-wise -- each b128 feeds 4 lerps
            // per batch-pair immediately (fine-grained lgkmcnt interleave).
            f2 u0[16], u1[16];
            #pragma unroll
            for (int k = 0; k < 8; ++k) {
                const float4 t4 = *(const float4*)&twl[ll][tx][4 * k];
                const float dA = t4.y - t4.x;    // d[2k]   (batch-invariant)
                const float dB = t4.w - t4.z;    // d[2k+1]
                u0[2 * k]     = __builtin_elementwise_fma(s4v[0], (f2)dA, (f2)t4.x);
                u0[2 * k + 1] = __builtin_elementwise_fma(s4v[0], (f2)dB, (f2)t4.z);
                u1[2 * k]     = __builtin_elementwise_fma(s4v[1], (f2)dA, (f2)t4.x);
                u1[2 * k + 1] = __builtin_elementwise_fma(s4v[1], (f2)dB, (f2)t4.z);
            }

            // levels 1..4: contract s3, s2(center), s1, s0 — adjacent pairs
            #pragma unroll
            for (int q = 0; q < 2; ++q) {
                f2* u = q ? u1 : u0;
                #pragma unroll
                for (int r = 0; r < 8; ++r)
                    u[r] = __builtin_elementwise_fma(s3v[q], u[2 * r + 1] - u[2 * r], u[2 * r]);
                #pragma unroll
                for (int r = 0; r < 4; ++r)
                    u[r] = __builtin_elementwise_fma(S[q],   u[2 * r + 1] - u[2 * r], u[2 * r]);
                #pragma unroll
                for (int r = 0; r < 2; ++r)
                    u[r] = __builtin_elementwise_fma(s1v[q], u[2 * r + 1] - u[2 * r], u[2 * r]);
                f2 rv = __builtin_elementwise_fma(s0v[q], u[1] - u[0], u[0]);
                rv = __builtin_elementwise_min(__builtin_elementwise_max(rv, (f2)0.0f), (f2)1.0f);
                S[q] = rv;
            }
        }

        if (g < 3) {
            __syncthreads();   // all waves done reading this group's gates
            // stage next group (sigmoid prefetched regs)
            #pragma unroll
            for (int ll = 0; ll < 2; ++ll) {
                float4 sg;
                sg.x = sigm(pf[ll * 4 + 0]);
                sg.y = sigm(pf[ll * 4 + 1]);
                sg.z = sigm(pf[ll * 4 + 2]);
                sg.w = sigm(pf[ll * 4 + 3]);
                *(float4*)&twl[ll][tx][c0] = sg;
            }
            if (g < 2) {       // prefetch group g+2 (layers 2g+4, 2g+5), masked
                const float* tn = tg + (size_t)(2 * g + 4) * NPOS * GRID_N;
                #pragma unroll
                for (int ll = 0; ll < 2; ++ll) {
                    const bool need = gate_needed(tx, 2 * g + 4 + ll);
                    #pragma unroll
                    for (int k = 0; k < 4; ++k)
                        pf[ll * 4 + k] = need ? tn[((size_t)ll * NPOS + c0 + k) * GRID_N + gcol] : 0.0f;
                }
            }
            __syncthreads();   // next group's gates visible
        }
    }

    // ---- output straight from registers: state[:, ::4] for owned columns ----
    const int rel = tx - HALO;
    if (rel >= 0 && rel < TILE && (rel & 3) == 0) {
        const int mo = (start >> 2) + (rel >> 2);
        out[(c0 + 0) * MW + mo] = S[0].x;
        out[(c0 + 1) * MW + mo] = S[0].y;
        out[(c0 + 2) * MW + mo] = S[1].x;
        out[(c0 + 3) * MW + mo] = S[1].y;
    }
}

extern "C" void kernel_launch(void* const* d_in, const int* in_sizes, int n_in,
                              void* d_out, int out_size, void* d_ws, size_t ws_size,
                              hipStream_t stream) {
    const float* x  = (const float*)d_in[0];   // (32, 4096)
    const float* tg = (const float*)d_in[1];   // (8, 32, 16384)
    float* out = (float*)d_out;                // (32, 4096)
    ASIC_44186623541335_kernel<<<GRID_N / TILE, 512, 0, stream>>>(x, tg, out);
}